// Round 13
// baseline (123.413 us; speedup 1.0000x reference)
//
#include <hip/hip_runtime.h>
#include <hip/hip_bf16.h>

#define NNODES 8192
#define DIN 512
#define HD1 256
#define LATD 128
#define CAP 128   // bucket capacity; P(deg>128) < 1e-18 for Binom(262144, 1/8192)

typedef __attribute__((ext_vector_type(4))) float f32x4;
typedef __attribute__((ext_vector_type(8))) short short8;

__device__ __forceinline__ float bf2f(uint u){
  union { uint i; float f; } v; v.i = u << 16; return v.f;
}
__device__ __forceinline__ ushort f2bf(float f){
  union { float f; uint i; } v; v.f = f;
  uint i = v.i;
  i += 0x7FFFu + ((i >> 16) & 1u);
  return (ushort)(i >> 16);
}

// ---------------- k_init: zero cnt + W1b (row-major bf16) + W2t/Wct (transposed bf16) ----------------

__global__ __launch_bounds__(256) void k_init(const float* __restrict__ W1,
    const float* __restrict__ W2, const float* __restrict__ Wmu,
    const float* __restrict__ Wlv, int* __restrict__ cnt,
    ushort* __restrict__ W1b, ushort* __restrict__ W2t, ushort* __restrict__ Wct)
{
  const int stride = gridDim.x * 256;
  const int gid = blockIdx.x * 256 + threadIdx.x;
  if (gid < NNODES) cnt[gid] = 0;
  // W1b row-major [512][256]
  for (int j = gid; j < DIN * HD1 / 4; j += stride){
    float4 v = *(const float4*)(W1 + j * 4);
    uint2 wv;
    wv.x = (uint)f2bf(v.x) | ((uint)f2bf(v.y) << 16);
    wv.y = (uint)f2bf(v.z) | ((uint)f2bf(v.w) << 16);
    *(uint2*)(W1b + j * 4) = wv;
  }
  // W2t [128 n][256 k]
  for (int j = gid; j < LATD * (HD1 / 8); j += stride){
    const int kc = j >> 7, n = j & 127;
    short8 s;
    #pragma unroll
    for (int jj = 0; jj < 8; ++jj) s[jj] = (short)f2bf(W2[(size_t)(kc * 8 + jj) * LATD + n]);
    *(short8*)(W2t + (size_t)n * HD1 + kc * 8) = s;
  }
  // Wct [256 n][128 k] = [Wmu|Wlv]^T
  for (int j = gid; j < 2 * LATD * (LATD / 8); j += stride){
    const int kc = j >> 8, n = j & 255;
    short8 s;
    if (n < LATD){
      #pragma unroll
      for (int jj = 0; jj < 8; ++jj) s[jj] = (short)f2bf(Wmu[(size_t)(kc * 8 + jj) * LATD + n]);
    } else {
      #pragma unroll
      for (int jj = 0; jj < 8; ++jj) s[jj] = (short)f2bf(Wlv[(size_t)(kc * 8 + jj) * LATD + n - LATD]);
    }
    *(short8*)(Wct + (size_t)n * LATD + kc * 8) = s;
  }
}

// ---------------- fused: bucket CSR fill + gemm1 (LDS staged) ----------------

__global__ __launch_bounds__(256) void k_fill_gemm1(const int* __restrict__ erow,
    const int* __restrict__ ecol, int E, int nbF,
    int* __restrict__ cursor, int* __restrict__ csr,
    const float* __restrict__ x, const ushort* __restrict__ W1b, ushort* __restrict__ h1)
{
  if ((int)blockIdx.x < nbF){
    int e = blockIdx.x * 256 + threadIdx.x;
    if (e < E){
      int r = erow[e], c = ecol[e];
      int pos = atomicAdd(&cursor[c], 1);
      if (pos < CAP) csr[(size_t)c * CAP + pos] = r;
    }
    return;
  }
  const int bx = blockIdx.x - nbF;
  const int n0 = (bx & 3) * 64, m0 = (bx >> 2) * 64;
  __shared__ ushort Al[64][40];
  __shared__ ushort Bl[64][40];   // transposed: Bl[n][k]
  const int t = threadIdx.x, w = t >> 6, l = t & 63, lr = l & 15, lk = l >> 4;
  const int wm = (w >> 1) * 32, wn = (w & 1) * 32;
  f32x4 acc[2][2] = {};
  for (int kt = 0; kt < DIN / 32; ++kt){
    {
      const int row = t >> 2, ch = t & 3;
      const float* ap = x + (size_t)(m0 + row) * DIN + kt * 32 + ch * 8;
      float4 v0 = *(const float4*)ap;
      float4 v1 = *(const float4*)(ap + 4);
      ushort* d = &Al[row][ch * 8];
      d[0] = f2bf(v0.x); d[1] = f2bf(v0.y); d[2] = f2bf(v0.z); d[3] = f2bf(v0.w);
      d[4] = f2bf(v1.x); d[5] = f2bf(v1.y); d[6] = f2bf(v1.z); d[7] = f2bf(v1.w);
      const int kk = t >> 3, nn = (t & 7) * 8;
      short8 bv = *(const short8*)(W1b + (size_t)(kt * 32 + kk) * HD1 + n0 + nn);
      #pragma unroll
      for (int i = 0; i < 8; ++i) Bl[nn + i][kk] = ((ushort*)&bv)[i];
    }
    __syncthreads();
    short8 a0 = *(const short8*)(&Al[wm + lr][lk * 8]);
    short8 a1 = *(const short8*)(&Al[wm + 16 + lr][lk * 8]);
    short8 b0 = *(const short8*)(&Bl[wn + lr][lk * 8]);
    short8 b1 = *(const short8*)(&Bl[wn + 16 + lr][lk * 8]);
    acc[0][0] = __builtin_amdgcn_mfma_f32_16x16x32_bf16(a0, b0, acc[0][0], 0, 0, 0);
    acc[0][1] = __builtin_amdgcn_mfma_f32_16x16x32_bf16(a0, b1, acc[0][1], 0, 0, 0);
    acc[1][0] = __builtin_amdgcn_mfma_f32_16x16x32_bf16(a1, b0, acc[1][0], 0, 0, 0);
    acc[1][1] = __builtin_amdgcn_mfma_f32_16x16x32_bf16(a1, b1, acc[1][1], 0, 0, 0);
    __syncthreads();
  }
  #pragma unroll
  for (int mi = 0; mi < 2; ++mi){
    #pragma unroll
    for (int ni = 0; ni < 2; ++ni){
      const int row = m0 + wm + mi * 16 + lk * 4;
      const int col = n0 + wn + ni * 16 + lr;
      #pragma unroll
      for (int r = 0; r < 4; ++r)
        h1[(size_t)(row + r) * HD1 + col] = f2bf(acc[mi][ni][r]);
    }
  }
}

// ---------------- fused agg1 + gemm2: 1024 thr, 16 waves, ONE node per wave ----------------
// Phase 1: wave w aggregates node vbase+w (F=256) -> z1t LDS (relu+bias).
// Phase 2: h2[16][128] = z1t @ W2t (waves 0-7 own n-tiles of 16).

__global__ __launch_bounds__(1024) void k_agg1_gemm2(const ushort* __restrict__ h1,
    const float* __restrict__ b1, const int* __restrict__ cnt,
    const int* __restrict__ csr, const ushort* __restrict__ W2t,
    ushort* __restrict__ h2)
{
  __shared__ ushort z1t[16][264];
  __shared__ int2 meta[16][64];
  const int t = threadIdx.x, w = t >> 6, l = t & 63, lr = l & 15, lk = l >> 4;
  const int vbase = blockIdx.x * 16;
  const int sub = l >> 5;          // F=256: LPE=32, EPI=2
  const int eb = (l & 31) * 8;
  {
    const int v = vbase + w;
    const int deg = min(cnt[v], CAP);
    const float dv = rsqrtf((float)(deg + 2));   // +2 self-loops
    float acc[8] = {0.f,0.f,0.f,0.f,0.f,0.f,0.f,0.f};
    const int beg = v * CAP, end = beg + deg;
    for (int base = beg; base < end; base += 64){
      const int cc = min(64, end - base);
      int idx = 0; float nr = 0.f;
      if (base + l < end){
        idx = csr[base + l];
        nr = rsqrtf((float)(min(cnt[idx], CAP) + 2)) * dv;
      }
      int2 m; m.x = idx; m.y = __float_as_int(nr);
      meta[w][l] = m;
      asm volatile("s_waitcnt lgkmcnt(0)" ::: "memory");
      const int nIt = (cc + 1) >> 1;
      for (int it = 0; it < nIt; ++it){
        int2 mm = meta[w][it * 2 + sub];
        const float nrr = __int_as_float(mm.y);
        const uint4 r = *(const uint4*)(h1 + (size_t)mm.x * HD1 + eb);
        acc[0] += nrr * bf2f(r.x & 0xffff); acc[1] += nrr * bf2f(r.x >> 16);
        acc[2] += nrr * bf2f(r.y & 0xffff); acc[3] += nrr * bf2f(r.y >> 16);
        acc[4] += nrr * bf2f(r.z & 0xffff); acc[5] += nrr * bf2f(r.z >> 16);
        acc[6] += nrr * bf2f(r.w & 0xffff); acc[7] += nrr * bf2f(r.w >> 16);
      }
      asm volatile("s_waitcnt lgkmcnt(0)" ::: "memory");
    }
    #pragma unroll
    for (int j = 0; j < 8; ++j) acc[j] += __shfl_xor(acc[j], 32);
    if (l < 32){
      const float ss = 2.f * dv * dv;
      const uint4 r = *(const uint4*)(h1 + (size_t)v * HD1 + eb);
      acc[0] += ss * bf2f(r.x & 0xffff); acc[1] += ss * bf2f(r.x >> 16);
      acc[2] += ss * bf2f(r.y & 0xffff); acc[3] += ss * bf2f(r.y >> 16);
      acc[4] += ss * bf2f(r.z & 0xffff); acc[5] += ss * bf2f(r.z >> 16);
      acc[6] += ss * bf2f(r.w & 0xffff); acc[7] += ss * bf2f(r.w >> 16);
      float4 b0 = *(const float4*)(b1 + eb);
      float4 bq = *(const float4*)(b1 + eb + 4);
      acc[0] += b0.x; acc[1] += b0.y; acc[2] += b0.z; acc[3] += b0.w;
      acc[4] += bq.x; acc[5] += bq.y; acc[6] += bq.z; acc[7] += bq.w;
      #pragma unroll
      for (int j = 0; j < 8; ++j) acc[j] = fmaxf(acc[j], 0.f);   // relu
      uint4 o;
      o.x = (uint)f2bf(acc[0]) | ((uint)f2bf(acc[1]) << 16);
      o.y = (uint)f2bf(acc[2]) | ((uint)f2bf(acc[3]) << 16);
      o.z = (uint)f2bf(acc[4]) | ((uint)f2bf(acc[5]) << 16);
      o.w = (uint)f2bf(acc[6]) | ((uint)f2bf(acc[7]) << 16);
      *(uint4*)(&z1t[w][eb]) = o;
    }
  }
  __syncthreads();
  // phase 2: waves 0-7 -> n-tile n0 = w*16, K=256
  if (w < 8){
    f32x4 acc2 = {0.f,0.f,0.f,0.f};
    #pragma unroll
    for (int kt = 0; kt < HD1 / 32; ++kt){
      const int ko = kt * 32 + lk * 8;
      short8 a = *(const short8*)(&z1t[lr][ko]);
      short8 b = *(const short8*)(W2t + (size_t)(w * 16 + lr) * HD1 + ko);
      acc2 = __builtin_amdgcn_mfma_f32_16x16x32_bf16(a, b, acc2, 0, 0, 0);
    }
    const int col = w * 16 + lr;
    #pragma unroll
    for (int r = 0; r < 4; ++r)
      h2[(size_t)(vbase + lk * 4 + r) * LATD + col] = f2bf(acc2[r]);
  }
}

// ---------------- fused agg2 + mu/lv: 1024 thr, 16 waves, ONE node per wave ----------------
// Phase 1: wave w aggregates node vbase+w (F=128) + b2 -> z2t LDS.
// Phase 2: [16][256] = z2t @ Wct; waves 0-7 -> mu (f32+bf16), 8-15 -> lv (f32).

__global__ __launch_bounds__(1024) void k_agg2_mulv(const ushort* __restrict__ h2,
    const float* __restrict__ b2, const int* __restrict__ cnt,
    const int* __restrict__ csr, const ushort* __restrict__ Wct,
    const float* __restrict__ bmu, const float* __restrict__ blv,
    float* __restrict__ mu, ushort* __restrict__ mu_bf, float* __restrict__ lv)
{
  __shared__ ushort z2t[16][136];
  __shared__ int2 meta[16][64];
  const int t = threadIdx.x, w = t >> 6, l = t & 63, lr = l & 15, lk = l >> 4;
  const int vbase = blockIdx.x * 16;
  const int sub = l >> 4;          // F=128: LPE=16, EPI=4
  const int eb = (l & 15) * 8;
  {
    const int v = vbase + w;
    const int deg = min(cnt[v], CAP);
    const float dv = rsqrtf((float)(deg + 2));
    float acc[8] = {0.f,0.f,0.f,0.f,0.f,0.f,0.f,0.f};
    const int beg = v * CAP, end = beg + deg;
    for (int base = beg; base < end; base += 64){
      const int cc = min(64, end - base);
      int idx = 0; float nr = 0.f;
      if (base + l < end){
        idx = csr[base + l];
        nr = rsqrtf((float)(min(cnt[idx], CAP) + 2)) * dv;
      }
      int2 m; m.x = idx; m.y = __float_as_int(nr);
      meta[w][l] = m;
      asm volatile("s_waitcnt lgkmcnt(0)" ::: "memory");
      const int nIt = (cc + 3) >> 2;
      for (int it = 0; it < nIt; ++it){
        int2 mm = meta[w][it * 4 + sub];
        const float nrr = __int_as_float(mm.y);
        const uint4 r = *(const uint4*)(h2 + (size_t)mm.x * LATD + eb);
        acc[0] += nrr * bf2f(r.x & 0xffff); acc[1] += nrr * bf2f(r.x >> 16);
        acc[2] += nrr * bf2f(r.y & 0xffff); acc[3] += nrr * bf2f(r.y >> 16);
        acc[4] += nrr * bf2f(r.z & 0xffff); acc[5] += nrr * bf2f(r.z >> 16);
        acc[6] += nrr * bf2f(r.w & 0xffff); acc[7] += nrr * bf2f(r.w >> 16);
      }
      asm volatile("s_waitcnt lgkmcnt(0)" ::: "memory");
    }
    #pragma unroll
    for (int off = 16; off < 64; off <<= 1){
      #pragma unroll
      for (int j = 0; j < 8; ++j) acc[j] += __shfl_xor(acc[j], off);
    }
    if (l < 16){
      const float ss = 2.f * dv * dv;
      const uint4 r = *(const uint4*)(h2 + (size_t)v * LATD + eb);
      acc[0] += ss * bf2f(r.x & 0xffff); acc[1] += ss * bf2f(r.x >> 16);
      acc[2] += ss * bf2f(r.y & 0xffff); acc[3] += ss * bf2f(r.y >> 16);
      acc[4] += ss * bf2f(r.z & 0xffff); acc[5] += ss * bf2f(r.z >> 16);
      acc[6] += ss * bf2f(r.w & 0xffff); acc[7] += ss * bf2f(r.w >> 16);
      float4 b0 = *(const float4*)(b2 + eb);
      float4 bq = *(const float4*)(b2 + eb + 4);
      acc[0] += b0.x; acc[1] += b0.y; acc[2] += b0.z; acc[3] += b0.w;
      acc[4] += bq.x; acc[5] += bq.y; acc[6] += bq.z; acc[7] += bq.w;
      uint4 o;
      o.x = (uint)f2bf(acc[0]) | ((uint)f2bf(acc[1]) << 16);
      o.y = (uint)f2bf(acc[2]) | ((uint)f2bf(acc[3]) << 16);
      o.z = (uint)f2bf(acc[4]) | ((uint)f2bf(acc[5]) << 16);
      o.w = (uint)f2bf(acc[6]) | ((uint)f2bf(acc[7]) << 16);
      *(uint4*)(&z2t[w][eb]) = o;
    }
  }
  __syncthreads();
  // phase 2: wave w -> n-tile w*16 of 256 cols, K=128
  {
    f32x4 acc2 = {0.f,0.f,0.f,0.f};
    #pragma unroll
    for (int kt = 0; kt < LATD / 32; ++kt){
      const int ko = kt * 32 + lk * 8;
      short8 a = *(const short8*)(&z2t[lr][ko]);
      short8 b = *(const short8*)(Wct + (size_t)(w * 16 + lr) * LATD + ko);
      acc2 = __builtin_amdgcn_mfma_f32_16x16x32_bf16(a, b, acc2, 0, 0, 0);
    }
    if (w < 8){
      const int col = w * 16 + lr;        // < 128
      const float bb = bmu[col];
      #pragma unroll
      for (int r = 0; r < 4; ++r){
        const float vv = acc2[r] + bb;
        mu[(size_t)(vbase + lk * 4 + r) * LATD + col] = vv;
        mu_bf[(size_t)(vbase + lk * 4 + r) * LATD + col] = f2bf(vv);
      }
    } else {
      const int col = (w - 8) * 16 + lr;  // < 128
      const float bb = blv[col];
      #pragma unroll
      for (int r = 0; r < 4; ++r)
        lv[(size_t)(vbase + lk * 4 + r) * LATD + col] = acc2[r] + bb;
    }
  }
}

// ---------------- adj = sigmoid(mu @ mu^T), 128x128 tiles, f32 out (at write roofline) ----------------

__global__ __launch_bounds__(512) void gemm5_kernel(const ushort* __restrict__ mu,
                                                    float* __restrict__ adj)
{
  __shared__ char lds[65536];
  const int t = threadIdx.x;
  const int bj = blockIdx.x, bi = blockIdx.y;
  {
    const int row = t >> 2, ch = t & 3;
    const char* srcA = (const char*)(mu + (size_t)(bi * 128 + row) * LATD);
    const char* srcB = (const char*)(mu + (size_t)(bj * 128 + row) * LATD);
    char* dA = lds + row * 256;
    char* dB = lds + 32768 + row * 256;
    #pragma unroll
    for (int i = 0; i < 4; ++i){
      const int kb = ch * 64 + i * 16;
      const int sk = kb ^ ((row & 7) << 4);
      *(short8*)(dA + sk) = *(const short8*)(srcA + kb);
      *(short8*)(dB + sk) = *(const short8*)(srcB + kb);
    }
  }
  __syncthreads();
  const int wid = t >> 6, l = t & 63, lr = l & 15, lk = l >> 4;
  const int wm = (wid >> 2) * 64, wn = (wid & 3) * 32;
  f32x4 acc[4][2] = {};
  #pragma unroll
  for (int ks = 0; ks < 4; ++ks){
    short8 a[4], b[2];
    const int kb = ks * 64 + lk * 16;
    #pragma unroll
    for (int mi = 0; mi < 4; ++mi){
      const int r = wm + mi * 16 + lr;
      a[mi] = *(const short8*)(lds + r * 256 + (kb ^ ((r & 7) << 4)));
    }
    #pragma unroll
    for (int ni = 0; ni < 2; ++ni){
      const int r = wn + ni * 16 + lr;
      b[ni] = *(const short8*)(lds + 32768 + r * 256 + (kb ^ ((r & 7) << 4)));
    }
    #pragma unroll
    for (int mi = 0; mi < 4; ++mi)
      #pragma unroll
      for (int ni = 0; ni < 2; ++ni)
        acc[mi][ni] = __builtin_amdgcn_mfma_f32_16x16x32_bf16(a[mi], b[ni], acc[mi][ni], 0, 0, 0);
  }
  float* orow = adj + (size_t)(bi * 128 + wm + lk * 4) * NNODES + bj * 128 + wn + lr;
  #pragma unroll
  for (int mi = 0; mi < 4; ++mi){
    #pragma unroll
    for (int ni = 0; ni < 2; ++ni){
      #pragma unroll
      for (int r = 0; r < 4; ++r){
        const float x = acc[mi][ni][r];
        orow[(size_t)(mi * 16 + r) * NNODES + ni * 16] = 1.f / (1.f + __expf(-x));
      }
    }
  }
}

// ---------------- launch ----------------

extern "C" void kernel_launch(void* const* d_in, const int* in_sizes, int n_in,
                              void* d_out, int out_size, void* d_ws, size_t ws_size,
                              hipStream_t stream)
{
  const float* x    = (const float*)d_in[0];
  const int*   ei   = (const int*)d_in[1];
  const float* W1   = (const float*)d_in[2];
  const float* b1   = (const float*)d_in[3];
  const float* W2   = (const float*)d_in[4];
  const float* b2   = (const float*)d_in[5];
  const float* Wmu  = (const float*)d_in[6];
  const float* bmu  = (const float*)d_in[7];
  const float* Wlv  = (const float*)d_in[8];
  const float* blv  = (const float*)d_in[9];
  const int E = in_sizes[1] / 2;
  const int* erow = ei;
  const int* ecol = ei + E;

  char* ws = (char*)d_ws;
  int*    cnt   = (int*)(ws);                  // 32KB
  ushort* W1b   = (ushort*)(ws + 65536);       // 256KB [512][256]
  ushort* W2t   = (ushort*)(ws + 327680);      // 64KB  [128][256]
  ushort* Wct   = (ushort*)(ws + 393216);      // 64KB  [256][128]
  int*    csr   = (int*)(ws + 1048576);        // 4MB buckets
  ushort* h1    = (ushort*)(ws + 8388608);     // 4MB (8192x256)
  ushort* h2    = (ushort*)(ws + 12582912);    // 2MB (8192x128)
  ushort* mu_bf = (ushort*)(ws + 14680064);    // 2MB

  float* adj = (float*)d_out;
  float* mu  = adj + (size_t)NNODES * NNODES;
  float* lv  = mu + (size_t)NNODES * LATD;

  const int nbF = (E + 255) / 256;

  // zero cnt + bf16 weights (W1 row-major, W2/Wc transposed)
  k_init<<<128, 256, 0, stream>>>(W1, W2, Wmu, Wlv, cnt, W1b, W2t, Wct);
  // fused: bucket CSR fill + gemm1 (h1 = bf16(x) @ W1b)
  k_fill_gemm1<<<nbF + 4 * (NNODES / 64), 256, 0, stream>>>(
      erow, ecol, E, nbF, cnt, csr, x, W1b, h1);
  // z1 (LDS-only) = relu(S·h1 + b1) ; h2 = z1 @ W2   [16 waves, 1 node/wave]
  k_agg1_gemm2<<<NNODES / 16, 1024, 0, stream>>>(h1, b1, cnt, csr, W2t, h2);
  // z2 (LDS-only) = S·h2 + b2 ; mu / lv = z2 @ [Wmu|Wlv]   [16 waves, 1 node/wave]
  k_agg2_mulv<<<NNODES / 16, 1024, 0, stream>>>(h2, b2, cnt, csr, Wct, bmu, blv, mu, mu_bf, lv);
  // adj = sigmoid(mu @ mu^T)
  gemm5_kernel<<<dim3(NNODES / 128, NNODES / 128), 512, 0, stream>>>(mu_bf, adj);
}

// Round 14
// 119.299 us; speedup vs baseline: 1.0345x; 1.0345x over previous
//
#include <hip/hip_runtime.h>
#include <hip/hip_bf16.h>

#define NNODES 8192
#define DIN 512
#define HD1 256
#define LATD 128
#define CAP 128   // bucket capacity; P(deg>128) < 1e-18 for Binom(262144, 1/8192)

typedef __attribute__((ext_vector_type(4))) float f32x4;
typedef __attribute__((ext_vector_type(8))) short short8;

__device__ __forceinline__ float bf2f(uint u){
  union { uint i; float f; } v; v.i = u << 16; return v.f;
}
__device__ __forceinline__ ushort f2bf(float f){
  union { float f; uint i; } v; v.f = f;
  uint i = v.i;
  i += 0x7FFFu + ((i >> 16) & 1u);
  return (ushort)(i >> 16);
}

// ---------------- k_init: zero cnt + W1b (row-major bf16) + W2t/Wct (transposed bf16) ----------------

__global__ __launch_bounds__(256) void k_init(const float* __restrict__ W1,
    const float* __restrict__ W2, const float* __restrict__ Wmu,
    const float* __restrict__ Wlv, int* __restrict__ cnt,
    ushort* __restrict__ W1b, ushort* __restrict__ W2t, ushort* __restrict__ Wct)
{
  const int stride = gridDim.x * 256;
  const int gid = blockIdx.x * 256 + threadIdx.x;
  if (gid < NNODES) cnt[gid] = 0;
  // W1b row-major [512][256]
  for (int j = gid; j < DIN * HD1 / 4; j += stride){
    float4 v = *(const float4*)(W1 + j * 4);
    uint2 wv;
    wv.x = (uint)f2bf(v.x) | ((uint)f2bf(v.y) << 16);
    wv.y = (uint)f2bf(v.z) | ((uint)f2bf(v.w) << 16);
    *(uint2*)(W1b + j * 4) = wv;
  }
  // W2t [128 n][256 k]
  for (int j = gid; j < LATD * (HD1 / 8); j += stride){
    const int kc = j >> 7, n = j & 127;
    short8 s;
    #pragma unroll
    for (int jj = 0; jj < 8; ++jj) s[jj] = (short)f2bf(W2[(size_t)(kc * 8 + jj) * LATD + n]);
    *(short8*)(W2t + (size_t)n * HD1 + kc * 8) = s;
  }
  // Wct [256 n][128 k] = [Wmu|Wlv]^T
  for (int j = gid; j < 2 * LATD * (LATD / 8); j += stride){
    const int kc = j >> 8, n = j & 255;
    short8 s;
    if (n < LATD){
      #pragma unroll
      for (int jj = 0; jj < 8; ++jj) s[jj] = (short)f2bf(Wmu[(size_t)(kc * 8 + jj) * LATD + n]);
    } else {
      #pragma unroll
      for (int jj = 0; jj < 8; ++jj) s[jj] = (short)f2bf(Wlv[(size_t)(kc * 8 + jj) * LATD + n - LATD]);
    }
    *(short8*)(Wct + (size_t)n * LATD + kc * 8) = s;
  }
}

// ---------------- fused: bucket CSR fill + gemm1 (LDS staged) ----------------

__global__ __launch_bounds__(256) void k_fill_gemm1(const int* __restrict__ erow,
    const int* __restrict__ ecol, int E, int nbF,
    int* __restrict__ cursor, int* __restrict__ csr,
    const float* __restrict__ x, const ushort* __restrict__ W1b, ushort* __restrict__ h1)
{
  if ((int)blockIdx.x < nbF){
    int e = blockIdx.x * 256 + threadIdx.x;
    if (e < E){
      int r = erow[e], c = ecol[e];
      int pos = atomicAdd(&cursor[c], 1);
      if (pos < CAP) csr[(size_t)c * CAP + pos] = r;
    }
    return;
  }
  const int bx = blockIdx.x - nbF;
  const int n0 = (bx & 3) * 64, m0 = (bx >> 2) * 64;
  __shared__ ushort Al[64][40];
  __shared__ ushort Bl[64][40];   // transposed: Bl[n][k]
  const int t = threadIdx.x, w = t >> 6, l = t & 63, lr = l & 15, lk = l >> 4;
  const int wm = (w >> 1) * 32, wn = (w & 1) * 32;
  f32x4 acc[2][2] = {};
  for (int kt = 0; kt < DIN / 32; ++kt){
    {
      const int row = t >> 2, ch = t & 3;
      const float* ap = x + (size_t)(m0 + row) * DIN + kt * 32 + ch * 8;
      float4 v0 = *(const float4*)ap;
      float4 v1 = *(const float4*)(ap + 4);
      ushort* d = &Al[row][ch * 8];
      d[0] = f2bf(v0.x); d[1] = f2bf(v0.y); d[2] = f2bf(v0.z); d[3] = f2bf(v0.w);
      d[4] = f2bf(v1.x); d[5] = f2bf(v1.y); d[6] = f2bf(v1.z); d[7] = f2bf(v1.w);
      const int kk = t >> 3, nn = (t & 7) * 8;
      short8 bv = *(const short8*)(W1b + (size_t)(kt * 32 + kk) * HD1 + n0 + nn);
      #pragma unroll
      for (int i = 0; i < 8; ++i) Bl[nn + i][kk] = ((ushort*)&bv)[i];
    }
    __syncthreads();
    short8 a0 = *(const short8*)(&Al[wm + lr][lk * 8]);
    short8 a1 = *(const short8*)(&Al[wm + 16 + lr][lk * 8]);
    short8 b0 = *(const short8*)(&Bl[wn + lr][lk * 8]);
    short8 b1 = *(const short8*)(&Bl[wn + 16 + lr][lk * 8]);
    acc[0][0] = __builtin_amdgcn_mfma_f32_16x16x32_bf16(a0, b0, acc[0][0], 0, 0, 0);
    acc[0][1] = __builtin_amdgcn_mfma_f32_16x16x32_bf16(a0, b1, acc[0][1], 0, 0, 0);
    acc[1][0] = __builtin_amdgcn_mfma_f32_16x16x32_bf16(a1, b0, acc[1][0], 0, 0, 0);
    acc[1][1] = __builtin_amdgcn_mfma_f32_16x16x32_bf16(a1, b1, acc[1][1], 0, 0, 0);
    __syncthreads();
  }
  #pragma unroll
  for (int mi = 0; mi < 2; ++mi){
    #pragma unroll
    for (int ni = 0; ni < 2; ++ni){
      const int row = m0 + wm + mi * 16 + lk * 4;
      const int col = n0 + wn + ni * 16 + lr;
      #pragma unroll
      for (int r = 0; r < 4; ++r)
        h1[(size_t)(row + r) * HD1 + col] = f2bf(acc[mi][ni][r]);
    }
  }
}

// ---------------- fused agg1 + gemm2: z1 rows live only in LDS (R12-validated) ----------------
// 512 thr, 8 waves. Phase 1: wave w aggregates nodes vbase+w*2+{0,1} (F=256) -> z1t LDS.
// Phase 2: h2[16][128] = z1t @ W2t (wave w owns n-tile w*16).

__global__ __launch_bounds__(512) void k_agg1_gemm2(const ushort* __restrict__ h1,
    const float* __restrict__ b1, const int* __restrict__ cnt,
    const int* __restrict__ csr, const ushort* __restrict__ W2t,
    ushort* __restrict__ h2)
{
  __shared__ ushort z1t[16][264];
  __shared__ int2 meta[8][64];
  const int t = threadIdx.x, w = t >> 6, l = t & 63, lr = l & 15, lk = l >> 4;
  const int vbase = blockIdx.x * 16;
  const int sub = l >> 5;          // F=256: LPE=32, EPI=2
  const int eb = (l & 31) * 8;
  #pragma unroll
  for (int vi = 0; vi < 2; ++vi){
    const int v = vbase + w * 2 + vi;
    const int deg = min(cnt[v], CAP);
    const float dv = rsqrtf((float)(deg + 2));   // +2 self-loops
    float acc[8] = {0.f,0.f,0.f,0.f,0.f,0.f,0.f,0.f};
    const int beg = v * CAP, end = beg + deg;
    for (int base = beg; base < end; base += 64){
      const int cc = min(64, end - base);
      int idx = 0; float nr = 0.f;
      if (base + l < end){
        idx = csr[base + l];
        nr = rsqrtf((float)(min(cnt[idx], CAP) + 2)) * dv;
      }
      int2 m; m.x = idx; m.y = __float_as_int(nr);
      meta[w][l] = m;
      asm volatile("s_waitcnt lgkmcnt(0)" ::: "memory");
      const int nIt = (cc + 1) >> 1;
      for (int it = 0; it < nIt; ++it){
        int2 mm = meta[w][it * 2 + sub];
        const float nrr = __int_as_float(mm.y);
        const uint4 r = *(const uint4*)(h1 + (size_t)mm.x * HD1 + eb);
        acc[0] += nrr * bf2f(r.x & 0xffff); acc[1] += nrr * bf2f(r.x >> 16);
        acc[2] += nrr * bf2f(r.y & 0xffff); acc[3] += nrr * bf2f(r.y >> 16);
        acc[4] += nrr * bf2f(r.z & 0xffff); acc[5] += nrr * bf2f(r.z >> 16);
        acc[6] += nrr * bf2f(r.w & 0xffff); acc[7] += nrr * bf2f(r.w >> 16);
      }
      asm volatile("s_waitcnt lgkmcnt(0)" ::: "memory");
    }
    #pragma unroll
    for (int j = 0; j < 8; ++j) acc[j] += __shfl_xor(acc[j], 32);
    if (l < 32){
      const float ss = 2.f * dv * dv;
      const uint4 r = *(const uint4*)(h1 + (size_t)v * HD1 + eb);
      acc[0] += ss * bf2f(r.x & 0xffff); acc[1] += ss * bf2f(r.x >> 16);
      acc[2] += ss * bf2f(r.y & 0xffff); acc[3] += ss * bf2f(r.y >> 16);
      acc[4] += ss * bf2f(r.z & 0xffff); acc[5] += ss * bf2f(r.z >> 16);
      acc[6] += ss * bf2f(r.w & 0xffff); acc[7] += ss * bf2f(r.w >> 16);
      float4 b0 = *(const float4*)(b1 + eb);
      float4 bq = *(const float4*)(b1 + eb + 4);
      acc[0] += b0.x; acc[1] += b0.y; acc[2] += b0.z; acc[3] += b0.w;
      acc[4] += bq.x; acc[5] += bq.y; acc[6] += bq.z; acc[7] += bq.w;
      #pragma unroll
      for (int j = 0; j < 8; ++j) acc[j] = fmaxf(acc[j], 0.f);   // relu
      uint4 o;
      o.x = (uint)f2bf(acc[0]) | ((uint)f2bf(acc[1]) << 16);
      o.y = (uint)f2bf(acc[2]) | ((uint)f2bf(acc[3]) << 16);
      o.z = (uint)f2bf(acc[4]) | ((uint)f2bf(acc[5]) << 16);
      o.w = (uint)f2bf(acc[6]) | ((uint)f2bf(acc[7]) << 16);
      *(uint4*)(&z1t[w * 2 + vi][eb]) = o;
    }
  }
  __syncthreads();
  // phase 2: wave w -> n-tile n0 = w*16, K=256
  f32x4 acc2 = {0.f,0.f,0.f,0.f};
  #pragma unroll
  for (int kt = 0; kt < HD1 / 32; ++kt){
    const int ko = kt * 32 + lk * 8;
    short8 a = *(const short8*)(&z1t[lr][ko]);
    short8 b = *(const short8*)(W2t + (size_t)(w * 16 + lr) * HD1 + ko);
    acc2 = __builtin_amdgcn_mfma_f32_16x16x32_bf16(a, b, acc2, 0, 0, 0);
  }
  const int col = w * 16 + lr;
  #pragma unroll
  for (int r = 0; r < 4; ++r)
    h2[(size_t)(vbase + lk * 4 + r) * LATD + col] = f2bf(acc2[r]);
}

// ---------------- fused agg2 + mu/lv: z2 rows live only in LDS (R12-validated) ----------------
// 512 thr, 8 waves. Phase 1: wave w aggregates nodes vbase+w*2+{0,1} (F=128) + b2 -> z2t.
// Phase 2: [16][256] = z2t @ Wct; waves 0-3 -> mu (f32+bf16), 4-7 -> lv (f32).

__global__ __launch_bounds__(512) void k_agg2_mulv(const ushort* __restrict__ h2,
    const float* __restrict__ b2, const int* __restrict__ cnt,
    const int* __restrict__ csr, const ushort* __restrict__ Wct,
    const float* __restrict__ bmu, const float* __restrict__ blv,
    float* __restrict__ mu, ushort* __restrict__ mu_bf, float* __restrict__ lv)
{
  __shared__ ushort z2t[16][136];
  __shared__ int2 meta[8][64];
  const int t = threadIdx.x, w = t >> 6, l = t & 63, lr = l & 15, lk = l >> 4;
  const int vbase = blockIdx.x * 16;
  const int sub = l >> 4;          // F=128: LPE=16, EPI=4
  const int eb = (l & 15) * 8;
  #pragma unroll
  for (int vi = 0; vi < 2; ++vi){
    const int v = vbase + w * 2 + vi;
    const int deg = min(cnt[v], CAP);
    const float dv = rsqrtf((float)(deg + 2));
    float acc[8] = {0.f,0.f,0.f,0.f,0.f,0.f,0.f,0.f};
    const int beg = v * CAP, end = beg + deg;
    for (int base = beg; base < end; base += 64){
      const int cc = min(64, end - base);
      int idx = 0; float nr = 0.f;
      if (base + l < end){
        idx = csr[base + l];
        nr = rsqrtf((float)(min(cnt[idx], CAP) + 2)) * dv;
      }
      int2 m; m.x = idx; m.y = __float_as_int(nr);
      meta[w][l] = m;
      asm volatile("s_waitcnt lgkmcnt(0)" ::: "memory");
      const int nIt = (cc + 3) >> 2;
      for (int it = 0; it < nIt; ++it){
        int2 mm = meta[w][it * 4 + sub];
        const float nrr = __int_as_float(mm.y);
        const uint4 r = *(const uint4*)(h2 + (size_t)mm.x * LATD + eb);
        acc[0] += nrr * bf2f(r.x & 0xffff); acc[1] += nrr * bf2f(r.x >> 16);
        acc[2] += nrr * bf2f(r.y & 0xffff); acc[3] += nrr * bf2f(r.y >> 16);
        acc[4] += nrr * bf2f(r.z & 0xffff); acc[5] += nrr * bf2f(r.z >> 16);
        acc[6] += nrr * bf2f(r.w & 0xffff); acc[7] += nrr * bf2f(r.w >> 16);
      }
      asm volatile("s_waitcnt lgkmcnt(0)" ::: "memory");
    }
    #pragma unroll
    for (int off = 16; off < 64; off <<= 1){
      #pragma unroll
      for (int j = 0; j < 8; ++j) acc[j] += __shfl_xor(acc[j], off);
    }
    if (l < 16){
      const float ss = 2.f * dv * dv;
      const uint4 r = *(const uint4*)(h2 + (size_t)v * LATD + eb);
      acc[0] += ss * bf2f(r.x & 0xffff); acc[1] += ss * bf2f(r.x >> 16);
      acc[2] += ss * bf2f(r.y & 0xffff); acc[3] += ss * bf2f(r.y >> 16);
      acc[4] += ss * bf2f(r.z & 0xffff); acc[5] += ss * bf2f(r.z >> 16);
      acc[6] += ss * bf2f(r.w & 0xffff); acc[7] += ss * bf2f(r.w >> 16);
      float4 b0 = *(const float4*)(b2 + eb);
      float4 bq = *(const float4*)(b2 + eb + 4);
      acc[0] += b0.x; acc[1] += b0.y; acc[2] += b0.z; acc[3] += b0.w;
      acc[4] += bq.x; acc[5] += bq.y; acc[6] += bq.z; acc[7] += bq.w;
      uint4 o;
      o.x = (uint)f2bf(acc[0]) | ((uint)f2bf(acc[1]) << 16);
      o.y = (uint)f2bf(acc[2]) | ((uint)f2bf(acc[3]) << 16);
      o.z = (uint)f2bf(acc[4]) | ((uint)f2bf(acc[5]) << 16);
      o.w = (uint)f2bf(acc[6]) | ((uint)f2bf(acc[7]) << 16);
      *(uint4*)(&z2t[w * 2 + vi][eb]) = o;
    }
  }
  __syncthreads();
  // phase 2: wave w -> n-tiles (w*2+ni)*16, K=128
  f32x4 acc2[2] = {};
  #pragma unroll
  for (int kt = 0; kt < LATD / 32; ++kt){
    const int ko = kt * 32 + lk * 8;
    short8 a = *(const short8*)(&z2t[lr][ko]);
    #pragma unroll
    for (int ni = 0; ni < 2; ++ni){
      short8 b = *(const short8*)(Wct + (size_t)((w * 2 + ni) * 16 + lr) * LATD + ko);
      acc2[ni] = __builtin_amdgcn_mfma_f32_16x16x32_bf16(a, b, acc2[ni], 0, 0, 0);
    }
  }
  if (w < 4){
    #pragma unroll
    for (int ni = 0; ni < 2; ++ni){
      const int col = (w * 2 + ni) * 16 + lr;        // < 128
      const float bb = bmu[col];
      #pragma unroll
      for (int r = 0; r < 4; ++r){
        const float vv = acc2[ni][r] + bb;
        mu[(size_t)(vbase + lk * 4 + r) * LATD + col] = vv;
        mu_bf[(size_t)(vbase + lk * 4 + r) * LATD + col] = f2bf(vv);
      }
    }
  } else {
    #pragma unroll
    for (int ni = 0; ni < 2; ++ni){
      const int col = ((w - 4) * 2 + ni) * 16 + lr;  // < 128
      const float bb = blv[col];
      #pragma unroll
      for (int r = 0; r < 4; ++r)
        lv[(size_t)(vbase + lk * 4 + r) * LATD + col] = acc2[ni][r] + bb;
    }
  }
}

// ---------------- adj = sigmoid(mu @ mu^T), 128x128 tiles, f32 out (write roofline) ----------------

__global__ __launch_bounds__(512) void gemm5_kernel(const ushort* __restrict__ mu,
                                                    float* __restrict__ adj)
{
  __shared__ char lds[65536];
  const int t = threadIdx.x;
  const int bj = blockIdx.x, bi = blockIdx.y;
  {
    const int row = t >> 2, ch = t & 3;
    const char* srcA = (const char*)(mu + (size_t)(bi * 128 + row) * LATD);
    const char* srcB = (const char*)(mu + (size_t)(bj * 128 + row) * LATD);
    char* dA = lds + row * 256;
    char* dB = lds + 32768 + row * 256;
    #pragma unroll
    for (int i = 0; i < 4; ++i){
      const int kb = ch * 64 + i * 16;
      const int sk = kb ^ ((row & 7) << 4);
      *(short8*)(dA + sk) = *(const short8*)(srcA + kb);
      *(short8*)(dB + sk) = *(const short8*)(srcB + kb);
    }
  }
  __syncthreads();
  const int wid = t >> 6, l = t & 63, lr = l & 15, lk = l >> 4;
  const int wm = (wid >> 2) * 64, wn = (wid & 3) * 32;
  f32x4 acc[4][2] = {};
  #pragma unroll
  for (int ks = 0; ks < 4; ++ks){
    short8 a[4], b[2];
    const int kb = ks * 64 + lk * 16;
    #pragma unroll
    for (int mi = 0; mi < 4; ++mi){
      const int r = wm + mi * 16 + lr;
      a[mi] = *(const short8*)(lds + r * 256 + (kb ^ ((r & 7) << 4)));
    }
    #pragma unroll
    for (int ni = 0; ni < 2; ++ni){
      const int r = wn + ni * 16 + lr;
      b[ni] = *(const short8*)(lds + 32768 + r * 256 + (kb ^ ((r & 7) << 4)));
    }
    #pragma unroll
    for (int mi = 0; mi < 4; ++mi)
      #pragma unroll
      for (int ni = 0; ni < 2; ++ni)
        acc[mi][ni] = __builtin_amdgcn_mfma_f32_16x16x32_bf16(a[mi], b[ni], acc[mi][ni], 0, 0, 0);
  }
  float* orow = adj + (size_t)(bi * 128 + wm + lk * 4) * NNODES + bj * 128 + wn + lr;
  #pragma unroll
  for (int mi = 0; mi < 4; ++mi){
    #pragma unroll
    for (int ni = 0; ni < 2; ++ni){
      #pragma unroll
      for (int r = 0; r < 4; ++r){
        const float x = acc[mi][ni][r];
        // sigmoid via raw HW rcp (no Newton refinement; |err| ~1e-6 << 1.7e-2 budget)
        orow[(size_t)(mi * 16 + r) * NNODES + ni * 16] =
            __builtin_amdgcn_rcpf(1.f + __expf(-x));
      }
    }
  }
}

// ---------------- launch ----------------

extern "C" void kernel_launch(void* const* d_in, const int* in_sizes, int n_in,
                              void* d_out, int out_size, void* d_ws, size_t ws_size,
                              hipStream_t stream)
{
  const float* x    = (const float*)d_in[0];
  const int*   ei   = (const int*)d_in[1];
  const float* W1   = (const float*)d_in[2];
  const float* b1   = (const float*)d_in[3];
  const float* W2   = (const float*)d_in[4];
  const float* b2   = (const float*)d_in[5];
  const float* Wmu  = (const float*)d_in[6];
  const float* bmu  = (const float*)d_in[7];
  const float* Wlv  = (const float*)d_in[8];
  const float* blv  = (const float*)d_in[9];
  const int E = in_sizes[1] / 2;
  const int* erow = ei;
  const int* ecol = ei + E;

  char* ws = (char*)d_ws;
  int*    cnt   = (int*)(ws);                  // 32KB
  ushort* W1b   = (ushort*)(ws + 65536);       // 256KB [512][256]
  ushort* W2t   = (ushort*)(ws + 327680);      // 64KB  [128][256]
  ushort* Wct   = (ushort*)(ws + 393216);      // 64KB  [256][128]
  int*    csr   = (int*)(ws + 1048576);        // 4MB buckets
  ushort* h1    = (ushort*)(ws + 8388608);     // 4MB (8192x256)
  ushort* h2    = (ushort*)(ws + 12582912);    // 2MB (8192x128)
  ushort* mu_bf = (ushort*)(ws + 14680064);    // 2MB

  float* adj = (float*)d_out;
  float* mu  = adj + (size_t)NNODES * NNODES;
  float* lv  = mu + (size_t)NNODES * LATD;

  const int nbF = (E + 255) / 256;

  // zero cnt + bf16 weights (W1 row-major, W2/Wc transposed)
  k_init<<<128, 256, 0, stream>>>(W1, W2, Wmu, Wlv, cnt, W1b, W2t, Wct);
  // fused: bucket CSR fill + gemm1 (h1 = bf16(x) @ W1b)
  k_fill_gemm1<<<nbF + 4 * (NNODES / 64), 256, 0, stream>>>(
      erow, ecol, E, nbF, cnt, csr, x, W1b, h1);
  // z1 (LDS-only) = relu(S·h1 + b1) ; h2 = z1 @ W2   [8 waves, 2 nodes/wave]
  k_agg1_gemm2<<<NNODES / 16, 512, 0, stream>>>(h1, b1, cnt, csr, W2t, h2);
  // z2 (LDS-only) = S·h2 + b2 ; mu / lv = z2 @ [Wmu|Wlv]   [8 waves, 2 nodes/wave]
  k_agg2_mulv<<<NNODES / 16, 512, 0, stream>>>(h2, b2, cnt, csr, Wct, bmu, blv, mu, mu_bf, lv);
  // adj = sigmoid(mu @ mu^T)
  gemm5_kernel<<<dim3(NNODES / 128, NNODES / 128), 512, 0, stream>>>(mu_bf, adj);
}